// Round 12
// baseline (134.535 us; speedup 1.0000x reference)
//
#include <hip/hip_runtime.h>
#include <hip/hip_bf16.h>

typedef __attribute__((ext_vector_type(8))) short bf16x8;
typedef __attribute__((ext_vector_type(4))) float f32x4;
typedef __attribute__((ext_vector_type(16))) float f32x16;
typedef __attribute__((ext_vector_type(2))) unsigned uint2v;

#define DEVI static __device__ __forceinline__

constexpr int Bb = 4, Tt = 2048, Cc = 1024, Hh = 16;
constexpr int Mrows = Bb * Tt;       // 8192
constexpr int KVdim = 256;           // 4 kv heads * 64
constexpr float LOG2E = 1.44269504088896340736f;

DEVI unsigned short f2bf(float f) {
  union { float f; unsigned u; } v; v.f = f;
  unsigned r = v.u + 0x7fffu + ((v.u >> 16) & 1u);
  return (unsigned short)(r >> 16);
}

DEVI f32x4 mfma16(bf16x8 a, bf16x8 b, f32x4 c) {
  return __builtin_amdgcn_mfma_f32_16x16x32_bf16(a, b, c, 0, 0, 0);
}
DEVI f32x16 mfma32(bf16x8 a, bf16x8 b, f32x16 c) {
  return __builtin_amdgcn_mfma_f32_32x32x16_bf16(a, b, c, 0, 0, 0);
}

DEVI unsigned cvtpk(float lo, float hi) {
  unsigned w;
  asm("v_cvt_pk_bf16_f32 %0, %1, %2" : "=v"(w) : "v"(lo), "v"(hi));
  return w;
}

DEVI void load_lds16(const void* g, void* s) {
  __builtin_amdgcn_global_load_lds(
      (const __attribute__((address_space(1))) void*)g,
      (__attribute__((address_space(3))) void*)s, 16, 0, 0);
}

// ---------------- fused fp32 -> bf16 convert (x + 4 weights) ----------------
__global__ __launch_bounds__(256) void cvt_all(
    const float* __restrict__ s0, const float* __restrict__ s1,
    const float* __restrict__ s2, const float* __restrict__ s3,
    const float* __restrict__ s4,
    unsigned short* __restrict__ d0, unsigned short* __restrict__ d1,
    unsigned short* __restrict__ d2, unsigned short* __restrict__ d3,
    unsigned short* __restrict__ d4,
    int n0, int n1, int n2, int n3, int n4) {
  const float* s; unsigned short* d; int n;
  switch (blockIdx.y) {
    case 0: s = s0; d = d0; n = n0; break;
    case 1: s = s1; d = d1; n = n1; break;
    case 2: s = s2; d = d2; n = n2; break;
    case 3: s = s3; d = d3; n = n3; break;
    default: s = s4; d = d4; n = n4; break;
  }
  int i = (blockIdx.x * 256 + threadIdx.x) * 4;
  const int stride = gridDim.x * 256 * 4;
  for (; i < n; i += stride) {
    float4 v = *(const float4*)(s + i);
    ushort4 o;
    o.x = f2bf(v.x); o.y = f2bf(v.y); o.z = f2bf(v.z); o.w = f2bf(v.w);
    *(ushort4*)(d + i) = o;
  }
}

// ---------------- fused QKV projection GEMM (T2-swizzled LDS) ----------------
// per-kk fragment loads: halve live A/B frags (64->32 regs) to chase the
// 128-reg occupancy quantum (m68/m69: 132+64acc rounded to 256 -> 2 blk/CU).
__global__ __launch_bounds__(256, 4) void qkv_gemm(const short* __restrict__ A,
                                                const short* __restrict__ wq,
                                                const short* __restrict__ wk,
                                                const short* __restrict__ wv,
                                                const float* __restrict__ bq,
                                                const float* __restrict__ bk,
                                                const float* __restrict__ bv,
                                                const float* __restrict__ gain,
                                                unsigned short* __restrict__ qout,
                                                unsigned short* __restrict__ kout,
                                                unsigned short* __restrict__ vout) {
  constexpr int K = Cc;
  __shared__ __align__(16) union QkvSmem {
    struct { short As[128 * 64]; short Bs[128 * 64]; } g;   // 32768 B
    unsigned short Ls[64][136];                             // 17408 B (V repack)
  } sm;
  short* As = sm.g.As;
  short* Bs = sm.g.Bs;
  const int tid = threadIdx.x;
  const int w = tid >> 6, l = tid & 63;
  const int l15 = l & 15, lg = l >> 4;
  const int m0 = blockIdx.x * 128, n0 = blockIdx.y * 128;

  const short* Bsrc; const float* bias; int mode;  // 0=Q,1=K,2=V
  if (n0 < 1024)      { Bsrc = wq + (size_t)n0 * K;          bias = bq + n0;          mode = 0; }
  else if (n0 < 1280) { Bsrc = wk + (size_t)(n0 - 1024) * K; bias = bk + (n0 - 1024); mode = 1; }
  else                { Bsrc = wv + (size_t)(n0 - 1280) * K; bias = bv + (n0 - 1280); mode = 2; }

  const int wr = (w >> 1) * 64, wc = (w & 1) * 64;
  f32x4 acc[4][4] = {};

  const int lrow = l >> 3;
  const int lchk = (l & 7) ^ (lrow & 7);          // inverse-swizzled source chunk
  const short* gA = A + (size_t)(m0 + w * 32 + lrow) * K + lchk * 8;
  const short* gB = Bsrc + (size_t)(w * 32 + lrow) * K + lchk * 8;
  short* lA = As + w * 32 * 64;
  short* lB = Bs + w * 32 * 64;
  const int sw = l15 & 7;                          // read-side XOR

  for (int k0 = 0; k0 < K; k0 += 64) {
#pragma unroll
    for (int i = 0; i < 4; ++i) {
      load_lds16(gA + (size_t)i * 8 * K, lA + i * 8 * 64);
      load_lds16(gB + (size_t)i * 8 * K, lB + i * 8 * 64);
    }
    gA += 64; gB += 64;
    __syncthreads();
#pragma unroll
    for (int kk = 0; kk < 2; ++kk) {
      bf16x8 af[4], bfr[4];
      const int ch = ((kk * 4 + lg) ^ sw) << 3;
#pragma unroll
      for (int i = 0; i < 4; ++i) {
        af[i] = *(const bf16x8*)(As + (wr + i * 16 + l15) * 64 + ch);
        bfr[i] = *(const bf16x8*)(Bs + (wc + i * 16 + l15) * 64 + ch);
      }
#pragma unroll
      for (int mi = 0; mi < 4; ++mi)
#pragma unroll
        for (int ni = 0; ni < 4; ++ni)
          acc[mi][ni] = mfma16(af[mi], bfr[ni], acc[mi][ni]);
    }
    __syncthreads();
  }

  const int crow = m0 + wr + lg * 4;
  if (mode == 2) {
    // V epilogue: LDS transpose repack -> coalesced [d][T] stores
    const int bb2 = m0 >> 11, tt0 = m0 & (Tt - 1);
#pragma unroll
    for (int colHalf = 0; colHalf < 2; ++colHalf) {
      if (colHalf) __syncthreads();
      if ((w & 1) == colHalf) {
#pragma unroll
        for (int ni = 0; ni < 4; ++ni) {
          const int c = ni * 16 + l15;
          const float bv_ = bias[colHalf * 64 + c];
#pragma unroll
          for (int mi = 0; mi < 4; ++mi)
#pragma unroll
            for (int r = 0; r < 4; ++r)
              sm.Ls[c][wr + lg * 4 + mi * 16 + r] = f2bf(acc[mi][ni][r] + bv_);
        }
      }
      __syncthreads();
      const int c = tid >> 2, ch = tid & 3;
      const int vcol = (n0 - 1280) + colHalf * 64 + c;
      unsigned short* dst = vout +
          ((size_t)((bb2 * 4 + (vcol >> 6)) * 64 + (vcol & 63))) * Tt + tt0 + ch * 32;
      const unsigned short* src = &sm.Ls[c][ch * 32];
#pragma unroll
      for (int q = 0; q < 4; ++q)
        *(bf16x8*)(dst + q * 8) = *(const bf16x8*)(src + q * 8);
    }
    return;
  }
#pragma unroll
  for (int ni = 0; ni < 4; ++ni) {
    const int lcol = wc + ni * 16 + l15;
    const float bv_ = bias[lcol];
    float sc = 1.f;
    if (mode == 0) sc = gain[(n0 + lcol) >> 6] * 0.125f * LOG2E;
#pragma unroll
    for (int mi = 0; mi < 4; ++mi) {
#pragma unroll
      for (int r = 0; r < 4; ++r) {
        const int row = crow + mi * 16 + r;
        float v = acc[mi][ni][r] + bv_;
        if (mode == 0) {
          qout[(size_t)row * Cc + n0 + lcol] = f2bf(v * sc);
        } else {
          kout[(size_t)row * KVdim + (n0 - 1024) + lcol] = f2bf(v);
        }
      }
    }
  }
}

// ---------------- O projection GEMM (bf16 A,B -> fp32 out, swizzled) ---------
__global__ __launch_bounds__(256, 4) void gemm_o(const short* __restrict__ A,
                                              const short* __restrict__ Bw,
                                              const float* __restrict__ bias,
                                              float* __restrict__ Cout,
                                              int M, int N, int K) {
  __shared__ __align__(16) short As[128 * 64];
  __shared__ __align__(16) short Bs[128 * 64];
  const int tid = threadIdx.x;
  const int w = tid >> 6, l = tid & 63;
  const int l15 = l & 15, lg = l >> 4;
  const int m0 = blockIdx.x * 128, n0 = blockIdx.y * 128;
  const int wr = (w >> 1) * 64, wc = (w & 1) * 64;
  f32x4 acc[4][4] = {};

  const int lrow = l >> 3;
  const int lchk = (l & 7) ^ (lrow & 7);
  const short* gA = A + (size_t)(m0 + w * 32 + lrow) * K + lchk * 8;
  const short* gB = Bw + (size_t)(n0 + w * 32 + lrow) * K + lchk * 8;
  short* lA = As + w * 32 * 64;
  short* lB = Bs + w * 32 * 64;
  const int sw = l15 & 7;

  for (int k0 = 0; k0 < K; k0 += 64) {
#pragma unroll
    for (int i = 0; i < 4; ++i) {
      load_lds16(gA + (size_t)i * 8 * K, lA + i * 8 * 64);
      load_lds16(gB + (size_t)i * 8 * K, lB + i * 8 * 64);
    }
    gA += 64; gB += 64;
    __syncthreads();
#pragma unroll
    for (int kk = 0; kk < 2; ++kk) {
      bf16x8 af[4], bfr[4];
      const int ch = ((kk * 4 + lg) ^ sw) << 3;
#pragma unroll
      for (int i = 0; i < 4; ++i) {
        af[i] = *(const bf16x8*)(As + (wr + i * 16 + l15) * 64 + ch);
        bfr[i] = *(const bf16x8*)(Bs + (wc + i * 16 + l15) * 64 + ch);
      }
#pragma unroll
      for (int mi = 0; mi < 4; ++mi)
#pragma unroll
        for (int ni = 0; ni < 4; ++ni)
          acc[mi][ni] = mfma16(af[mi], bfr[ni], acc[mi][ni]);
    }
    __syncthreads();
  }

  const int crow = m0 + wr + lg * 4;
  const int ccol = n0 + wc + l15;
#pragma unroll
  for (int ni = 0; ni < 4; ++ni) {
    const int col = ccol + ni * 16;
    const float bv = bias[col];
#pragma unroll
    for (int mi = 0; mi < 4; ++mi)
#pragma unroll
      for (int r = 0; r < 4; ++r)
        Cout[(size_t)(crow + mi * 16 + r) * N + col] = acc[mi][ni][r] + bv;
  }
}

// ---------------- flash attention v10: 4-deep LDS ring, 1 barrier/pair -------
#define PACK_SUB(pp, dst)                                        \
  {                                                              \
    unsigned Aw = cvtpk(pp[0], pp[1]), Bw_ = cvtpk(pp[2], pp[3]);\
    unsigned Cw = cvtpk(pp[4], pp[5]), Dw = cvtpk(pp[6], pp[7]); \
    uint2v xc = __builtin_amdgcn_permlane32_swap(Aw, Cw, false, false); \
    uint2v yd = __builtin_amdgcn_permlane32_swap(Bw_, Dw, false, false);\
    dst[0] = xc[0]; dst[1] = yd[0]; dst[2] = xc[1]; dst[3] = yd[1];     \
    Aw = cvtpk(pp[8], pp[9]); Bw_ = cvtpk(pp[10], pp[11]);       \
    Cw = cvtpk(pp[12], pp[13]); Dw = cvtpk(pp[14], pp[15]);      \
    xc = __builtin_amdgcn_permlane32_swap(Aw, Cw, false, false); \
    yd = __builtin_amdgcn_permlane32_swap(Bw_, Dw, false, false);\
    dst[4] = xc[0]; dst[5] = yd[0]; dst[6] = xc[1]; dst[7] = yd[1];     \
  }

// One 32-s half-tile from ring buffer BUF.
#define HALF(BUF, ROFF, CB)                                                   \
  {                                                                           \
    f32x16 sa = {};                                                           \
    _Pragma("unroll")                                                         \
    for (int c = 0; c < 4; ++c) {                                             \
      bf16x8 ka = *(const bf16x8*)&Ks[BUF][(ROFF) + l31][c * 16 + hi * 8];    \
      sa = mfma32(ka, qf[c], sa);                                             \
    }                                                                         \
    if (s0 + (ROFF) + 31 > qw0) {                                             \
      _Pragma("unroll")                                                       \
      for (int r = 0; r < 16; ++r) {                                          \
        const int sl = s0 + (ROFF) + (r & 3) + 8 * (r >> 2) + 4 * hi;         \
        if (sl > q_abs) sa[r] = -1e30f;                                       \
      }                                                                       \
    }                                                                         \
    _Pragma("unroll")                                                         \
    for (int r = 0; r < 16; ++r) sa[r] = exp2f(sa[r]);                        \
    {                                                                         \
      float a0 = (sa[0] + sa[1]) + (sa[2] + sa[3]);                           \
      float a1 = (sa[4] + sa[5]) + (sa[6] + sa[7]);                           \
      float a2 = (sa[8] + sa[9]) + (sa[10] + sa[11]);                         \
      float a3 = (sa[12] + sa[13]) + (sa[14] + sa[15]);                       \
      l_s += (a0 + a1) + (a2 + a3);                                           \
    }                                                                         \
    unsigned pw[8];                                                           \
    PACK_SUB(sa, pw);                                                         \
    _Pragma("unroll")                                                         \
    for (int t4 = 0; t4 < 2; ++t4) {                                          \
      union { unsigned u[4]; bf16x8 v; } pb;                                  \
      pb.u[0] = pw[t4 * 4 + 0]; pb.u[1] = pw[t4 * 4 + 1];                     \
      pb.u[2] = pw[t4 * 4 + 2]; pb.u[3] = pw[t4 * 4 + 3];                     \
      bf16x8 va0 = *(const bf16x8*)&Vt[BUF][l31][((CB) + t4) * 16 + hi * 8];  \
      bf16x8 va1 = *(const bf16x8*)&Vt[BUF][32 + l31][((CB) + t4) * 16 + hi * 8];\
      ot0 = mfma32(va0, pb.v, ot0);                                           \
      ot1 = mfma32(va1, pb.v, ot1);                                           \
    }                                                                         \
  }

// block = 512 thr = 8 waves: qsub = w&3, kpar = w>>2 (tile t%2==kpar).
// 4-deep LDS ring (tile t -> buf t&3): schedule per pair p is
//   [compute pair p] [barrier] [ds_write pair p+2] [issue loads pair p+3]
// -> ONE barrier per pair (attn9 had two). Every RAW/WAR pair is separated
// by >=1 barrier (write p+2 after bar_p, read p+2 after bar_{p+1}; write
// p+2 overwrites pair-p bufs whose reads finished before bar_p).
__global__ __launch_bounds__(512, 4) void attn10(const short* __restrict__ qb,
                                                 const short* __restrict__ kb,
                                                 const short* __restrict__ vtg,
                                                 unsigned short* __restrict__ ob) {
  __shared__ __align__(16) union SmemU {
    struct { short Ks[4][64][72]; short Vt[4][64][72]; } s;   // 73728 B
    struct { float red[256 * 32]; float redl[256]; } r;       // 33792 B
  } sm;
  auto& Ks = sm.s.Ks;
  auto& Vt = sm.s.Vt;

  const int tid = threadIdx.x, w = tid >> 6, l = tid & 63;
  const int l31 = l & 31, hi = l >> 5;
  const int qsub = w & 3, kpar = w >> 2;
  const int id = blockIdx.x;
  const int bh = id & 63, j = id >> 6;
  const int perm[16] = {15, 14, 13, 12, 8, 9, 10, 11, 7, 6, 5, 4, 0, 1, 2, 3};
  const int i128 = perm[j];
  const int b = bh >> 4, h = bh & 15, kv = h >> 2;
  const int q0 = i128 * 128;
  const int qw0 = q0 + qsub * 32;
  const int q_abs = qw0 + l31;

  const short* qp = qb + (size_t)(b * Tt + q_abs) * Cc + h * 64 + hi * 8;
  bf16x8 qf[4];
#pragma unroll
  for (int c = 0; c < 4; ++c) qf[c] = *(const bf16x8*)(qp + c * 16);

  f32x16 ot0 = {}, ot1 = {};
  float l_s = 0.f;

  // staging: tid 0..255 stage the even tile of each pair, 256..511 the odd
  const int half512 = tid >> 8;
  const int srow = (tid & 255) >> 2, scol = (tid & 3) * 16;
  const short* kst = kb + (size_t)(b * Tt + srow) * KVdim + kv * 64 + scol;
  const short* vst = vtg + (size_t)((b * 4 + kv) * 64 + srow) * Tt + scol;

  const int np = i128 + 1;                 // pairs of 64-s tiles

  bf16x8 rk0, rk1, rv0, rv1;
#define LOADP(p)                                                   \
  {                                                                \
    const int ts_ = 2 * (p) + half512;                             \
    const short* ks_ = kst + (size_t)ts_ * 64 * KVdim;             \
    const short* vs_ = vst + ts_ * 64;                             \
    rk0 = *(const bf16x8*)ks_;  rk1 = *(const bf16x8*)(ks_ + 8);   \
    rv0 = *(const bf16x8*)vs_;  rv1 = *(const bf16x8*)(vs_ + 8);   \
  }
#define WRITEP(p)                                                  \
  {                                                                \
    const int bu_ = (2 * (p) + half512) & 3;                       \
    *(bf16x8*)&Ks[bu_][srow][scol] = rk0;                          \
    *(bf16x8*)&Ks[bu_][srow][scol + 8] = rk1;                      \
    *(bf16x8*)&Vt[bu_][srow][scol] = rv0;                          \
    *(bf16x8*)&Vt[bu_][srow][scol + 8] = rv1;                      \
  }

  // prologue: fill pairs 0,1; preload pair 2 into regs
  LOADP(0); WRITEP(0);
  if (np > 1) { LOADP(1); WRITEP(1); }
  if (np > 2) LOADP(2);
  __syncthreads();

  for (int p = 0; p < np; ++p) {
    const int t = 2 * p + kpar;
    const int s0 = t * 64;
    const int bu = t & 3;
    if (s0 <= qw0 + 31) {
      HALF(bu, 0, 0);
      if (s0 + 32 <= qw0 + 31) HALF(bu, 32, 2);
    }
    __syncthreads();
    if (p + 2 < np) WRITEP(p + 2);
    if (p + 3 < np) LOADP(p + 3);
  }

  // combine kpar partners via LDS (overlaid reduction space),
  // conflict-free via per-lane chunk rotation cc=(c+l)&7
  float* red = sm.r.red;
  float* redl = sm.r.redl;
  const int rot = l & 7;
  if (kpar == 1) {
    float* p = red + ((qsub * 64 + l) * 32);
#pragma unroll
    for (int c = 0; c < 8; ++c) {
      const int cc = ((c + rot) & 7) * 4;
      f32x4 v;
      if (c < 4) {
        v[0] = ot0[c * 4]; v[1] = ot0[c * 4 + 1];
        v[2] = ot0[c * 4 + 2]; v[3] = ot0[c * 4 + 3];
      } else {
        const int b0 = (c - 4) * 4;
        v[0] = ot1[b0]; v[1] = ot1[b0 + 1];
        v[2] = ot1[b0 + 2]; v[3] = ot1[b0 + 3];
      }
      *(f32x4*)(p + cc) = v;
    }
    redl[qsub * 64 + l] = l_s;
  }
  __syncthreads();
  if (kpar == 0) {
    const float* p = red + ((qsub * 64 + l) * 32);
#pragma unroll
    for (int c = 0; c < 8; ++c) {
      const int cc = ((c + rot) & 7) * 4;
      f32x4 v = *(const f32x4*)(p + cc);
      if (c < 4) {
        ot0[c * 4] += v[0]; ot0[c * 4 + 1] += v[1];
        ot0[c * 4 + 2] += v[2]; ot0[c * 4 + 3] += v[3];
      } else {
        const int b0 = (c - 4) * 4;
        ot1[b0] += v[0]; ot1[b0 + 1] += v[1];
        ot1[b0 + 2] += v[2]; ot1[b0 + 3] += v[3];
      }
    }
    l_s += redl[qsub * 64 + l];
    l_s += __shfl_xor(l_s, 32);
    const float inv = 1.f / l_s;
    unsigned short* op = ob + (size_t)(b * Tt + q_abs) * Cc + h * 64;
#pragma unroll
    for (int r = 0; r < 16; ++r) {
      const int d = (r & 3) + 8 * (r >> 2) + 4 * hi;
      op[d] = f2bf(ot0[r] * inv);
      op[32 + d] = f2bf(ot1[r] * inv);
    }
  }
}

extern "C" void kernel_launch(void* const* d_in, const int* in_sizes, int n_in,
                              void* d_out, int out_size, void* d_ws, size_t ws_size,
                              hipStream_t stream) {
  (void)in_sizes; (void)n_in; (void)out_size; (void)ws_size;
  const float* x  = (const float*)d_in[0];
  const float* Wq = (const float*)d_in[1];
  const float* bq = (const float*)d_in[2];
  const float* Wk = (const float*)d_in[3];
  const float* bk = (const float*)d_in[4];
  const float* Wv = (const float*)d_in[5];
  const float* bv = (const float*)d_in[6];
  const float* Wo = (const float*)d_in[7];
  const float* bo = (const float*)d_in[8];
  const float* gain = (const float*)d_in[9];
  float* out = (float*)d_out;

  char* ws = (char*)d_ws;
  short* xb  = (short*)ws;                    ws += (size_t)Mrows * Cc * 2;
  short* qbf = (short*)ws;                    ws += (size_t)Mrows * Cc * 2;
  short* kbf = (short*)ws;                    ws += (size_t)Mrows * KVdim * 2;
  short* vtg = (short*)ws;                    ws += (size_t)Mrows * KVdim * 2;
  short* atb = (short*)ws;                    ws += (size_t)Mrows * Cc * 2;
  short* wqb = (short*)ws;                    ws += (size_t)Cc * Cc * 2;
  short* wkb = (short*)ws;                    ws += (size_t)KVdim * Cc * 2;
  short* wvb = (short*)ws;                    ws += (size_t)KVdim * Cc * 2;
  short* wob = (short*)ws;                    ws += (size_t)Cc * Cc * 2;

  cvt_all<<<dim3(1024, 5), 256, 0, stream>>>(
      x, Wq, Wk, Wv, Wo,
      (unsigned short*)xb, (unsigned short*)wqb, (unsigned short*)wkb,
      (unsigned short*)wvb, (unsigned short*)wob,
      Mrows * Cc, Cc * Cc, KVdim * Cc, KVdim * Cc, Cc * Cc);

  qkv_gemm<<<dim3(Mrows / 128, 12), 256, 0, stream>>>(
      xb, wqb, wkb, wvb, bq, bk, bv, gain,
      (unsigned short*)qbf, (unsigned short*)kbf, (unsigned short*)vtg);

  attn10<<<1024, 512, 0, stream>>>(qbf, kbf, vtg, (unsigned short*)atb);

  gemm_o<<<dim3(Mrows / 128, Cc / 128), 256, 0, stream>>>(
      atb, wob, bo, out, Mrows, Cc, Cc);
}

// Round 13
// 127.612 us; speedup vs baseline: 1.0542x; 1.0542x over previous
//
#include <hip/hip_runtime.h>
#include <hip/hip_bf16.h>

typedef __attribute__((ext_vector_type(8))) short bf16x8;
typedef __attribute__((ext_vector_type(4))) float f32x4;
typedef __attribute__((ext_vector_type(16))) float f32x16;
typedef __attribute__((ext_vector_type(2))) unsigned uint2v;

#define DEVI static __device__ __forceinline__

constexpr int Bb = 4, Tt = 2048, Cc = 1024, Hh = 16;
constexpr int Mrows = Bb * Tt;       // 8192
constexpr int KVdim = 256;           // 4 kv heads * 64
constexpr float LOG2E = 1.44269504088896340736f;

DEVI unsigned short f2bf(float f) {
  union { float f; unsigned u; } v; v.f = f;
  unsigned r = v.u + 0x7fffu + ((v.u >> 16) & 1u);
  return (unsigned short)(r >> 16);
}

DEVI f32x4 mfma16(bf16x8 a, bf16x8 b, f32x4 c) {
  return __builtin_amdgcn_mfma_f32_16x16x32_bf16(a, b, c, 0, 0, 0);
}
DEVI f32x16 mfma32(bf16x8 a, bf16x8 b, f32x16 c) {
  return __builtin_amdgcn_mfma_f32_32x32x16_bf16(a, b, c, 0, 0, 0);
}

DEVI unsigned cvtpk(float lo, float hi) {
  unsigned w;
  asm("v_cvt_pk_bf16_f32 %0, %1, %2" : "=v"(w) : "v"(lo), "v"(hi));
  return w;
}

DEVI void load_lds16(const void* g, void* s) {
  __builtin_amdgcn_global_load_lds(
      (const __attribute__((address_space(1))) void*)g,
      (__attribute__((address_space(3))) void*)s, 16, 0, 0);
}

// ---------------- fused fp32 -> bf16 convert (x + 4 weights) ----------------
__global__ __launch_bounds__(256) void cvt_all(
    const float* __restrict__ s0, const float* __restrict__ s1,
    const float* __restrict__ s2, const float* __restrict__ s3,
    const float* __restrict__ s4,
    unsigned short* __restrict__ d0, unsigned short* __restrict__ d1,
    unsigned short* __restrict__ d2, unsigned short* __restrict__ d3,
    unsigned short* __restrict__ d4,
    int n0, int n1, int n2, int n3, int n4) {
  const float* s; unsigned short* d; int n;
  switch (blockIdx.y) {
    case 0: s = s0; d = d0; n = n0; break;
    case 1: s = s1; d = d1; n = n1; break;
    case 2: s = s2; d = d2; n = n2; break;
    case 3: s = s3; d = d3; n = n3; break;
    default: s = s4; d = d4; n = n4; break;
  }
  int i = (blockIdx.x * 256 + threadIdx.x) * 4;
  const int stride = gridDim.x * 256 * 4;
  for (; i < n; i += stride) {
    float4 v = *(const float4*)(s + i);
    ushort4 o;
    o.x = f2bf(v.x); o.y = f2bf(v.y); o.z = f2bf(v.z); o.w = f2bf(v.w);
    *(ushort4*)(d + i) = o;
  }
}

// ---------------- fused QKV projection GEMM (T2-swizzled LDS) ----------------
__global__ __launch_bounds__(256, 4) void qkv_gemm(const short* __restrict__ A,
                                                const short* __restrict__ wq,
                                                const short* __restrict__ wk,
                                                const short* __restrict__ wv,
                                                const float* __restrict__ bq,
                                                const float* __restrict__ bk,
                                                const float* __restrict__ bv,
                                                const float* __restrict__ gain,
                                                unsigned short* __restrict__ qout,
                                                unsigned short* __restrict__ kout,
                                                unsigned short* __restrict__ vout) {
  constexpr int K = Cc;
  __shared__ __align__(16) union QkvSmem {
    struct { short As[128 * 64]; short Bs[128 * 64]; } g;   // 32768 B
    unsigned short Ls[64][136];                             // 17408 B (V repack)
  } sm;
  short* As = sm.g.As;
  short* Bs = sm.g.Bs;
  const int tid = threadIdx.x;
  const int w = tid >> 6, l = tid & 63;
  const int l15 = l & 15, lg = l >> 4;
  const int m0 = blockIdx.x * 128, n0 = blockIdx.y * 128;

  const short* Bsrc; const float* bias; int mode;  // 0=Q,1=K,2=V
  if (n0 < 1024)      { Bsrc = wq + (size_t)n0 * K;          bias = bq + n0;          mode = 0; }
  else if (n0 < 1280) { Bsrc = wk + (size_t)(n0 - 1024) * K; bias = bk + (n0 - 1024); mode = 1; }
  else                { Bsrc = wv + (size_t)(n0 - 1280) * K; bias = bv + (n0 - 1280); mode = 2; }

  const int wr = (w >> 1) * 64, wc = (w & 1) * 64;
  f32x4 acc[4][4] = {};

  const int lrow = l >> 3;
  const int lchk = (l & 7) ^ (lrow & 7);          // inverse-swizzled source chunk
  const short* gA = A + (size_t)(m0 + w * 32 + lrow) * K + lchk * 8;
  const short* gB = Bsrc + (size_t)(w * 32 + lrow) * K + lchk * 8;
  short* lA = As + w * 32 * 64;
  short* lB = Bs + w * 32 * 64;
  const int sw = l15 & 7;                          // read-side XOR

  for (int k0 = 0; k0 < K; k0 += 64) {
#pragma unroll
    for (int i = 0; i < 4; ++i) {
      load_lds16(gA + (size_t)i * 8 * K, lA + i * 8 * 64);
      load_lds16(gB + (size_t)i * 8 * K, lB + i * 8 * 64);
    }
    gA += 64; gB += 64;
    __syncthreads();
    bf16x8 af[2][4], bfr[2][4];
#pragma unroll
    for (int kk = 0; kk < 2; ++kk)
#pragma unroll
      for (int i = 0; i < 4; ++i) {
        const int ch = ((kk * 4 + lg) ^ sw) << 3;
        af[kk][i] = *(const bf16x8*)(As + (wr + i * 16 + l15) * 64 + ch);
        bfr[kk][i] = *(const bf16x8*)(Bs + (wc + i * 16 + l15) * 64 + ch);
      }
#pragma unroll
    for (int kk = 0; kk < 2; ++kk)
#pragma unroll
      for (int mi = 0; mi < 4; ++mi)
#pragma unroll
        for (int ni = 0; ni < 4; ++ni)
          acc[mi][ni] = mfma16(af[kk][mi], bfr[kk][ni], acc[mi][ni]);
    __syncthreads();
  }

  const int crow = m0 + wr + lg * 4;
  if (mode == 2) {
    // V epilogue: LDS transpose repack -> coalesced [d][T] stores
    const int bb2 = m0 >> 11, tt0 = m0 & (Tt - 1);
#pragma unroll
    for (int colHalf = 0; colHalf < 2; ++colHalf) {
      if (colHalf) __syncthreads();
      if ((w & 1) == colHalf) {
#pragma unroll
        for (int ni = 0; ni < 4; ++ni) {
          const int c = ni * 16 + l15;
          const float bv_ = bias[colHalf * 64 + c];
#pragma unroll
          for (int mi = 0; mi < 4; ++mi)
#pragma unroll
            for (int r = 0; r < 4; ++r)
              sm.Ls[c][wr + lg * 4 + mi * 16 + r] = f2bf(acc[mi][ni][r] + bv_);
        }
      }
      __syncthreads();
      const int c = tid >> 2, ch = tid & 3;
      const int vcol = (n0 - 1280) + colHalf * 64 + c;
      unsigned short* dst = vout +
          ((size_t)((bb2 * 4 + (vcol >> 6)) * 64 + (vcol & 63))) * Tt + tt0 + ch * 32;
      const unsigned short* src = &sm.Ls[c][ch * 32];
#pragma unroll
      for (int q = 0; q < 4; ++q)
        *(bf16x8*)(dst + q * 8) = *(const bf16x8*)(src + q * 8);
    }
    return;
  }
#pragma unroll
  for (int ni = 0; ni < 4; ++ni) {
    const int lcol = wc + ni * 16 + l15;
    const float bv_ = bias[lcol];
    float sc = 1.f;
    if (mode == 0) sc = gain[(n0 + lcol) >> 6] * 0.125f * LOG2E;
#pragma unroll
    for (int mi = 0; mi < 4; ++mi) {
#pragma unroll
      for (int r = 0; r < 4; ++r) {
        const int row = crow + mi * 16 + r;
        float v = acc[mi][ni][r] + bv_;
        if (mode == 0) {
          qout[(size_t)row * Cc + n0 + lcol] = f2bf(v * sc);
        } else {
          kout[(size_t)row * KVdim + (n0 - 1024) + lcol] = f2bf(v);
        }
      }
    }
  }
}

// ---------------- O projection GEMM (bf16 A,B -> fp32 out, swizzled) ---------
__global__ __launch_bounds__(256, 4) void gemm_o(const short* __restrict__ A,
                                              const short* __restrict__ Bw,
                                              const float* __restrict__ bias,
                                              float* __restrict__ Cout,
                                              int M, int N, int K) {
  __shared__ __align__(16) short As[128 * 64];
  __shared__ __align__(16) short Bs[128 * 64];
  const int tid = threadIdx.x;
  const int w = tid >> 6, l = tid & 63;
  const int l15 = l & 15, lg = l >> 4;
  const int m0 = blockIdx.x * 128, n0 = blockIdx.y * 128;
  const int wr = (w >> 1) * 64, wc = (w & 1) * 64;
  f32x4 acc[4][4] = {};

  const int lrow = l >> 3;
  const int lchk = (l & 7) ^ (lrow & 7);
  const short* gA = A + (size_t)(m0 + w * 32 + lrow) * K + lchk * 8;
  const short* gB = Bw + (size_t)(n0 + w * 32 + lrow) * K + lchk * 8;
  short* lA = As + w * 32 * 64;
  short* lB = Bs + w * 32 * 64;
  const int sw = l15 & 7;

  for (int k0 = 0; k0 < K; k0 += 64) {
#pragma unroll
    for (int i = 0; i < 4; ++i) {
      load_lds16(gA + (size_t)i * 8 * K, lA + i * 8 * 64);
      load_lds16(gB + (size_t)i * 8 * K, lB + i * 8 * 64);
    }
    gA += 64; gB += 64;
    __syncthreads();
    bf16x8 af[2][4], bfr[2][4];
#pragma unroll
    for (int kk = 0; kk < 2; ++kk)
#pragma unroll
      for (int i = 0; i < 4; ++i) {
        const int ch = ((kk * 4 + lg) ^ sw) << 3;
        af[kk][i] = *(const bf16x8*)(As + (wr + i * 16 + l15) * 64 + ch);
        bfr[kk][i] = *(const bf16x8*)(Bs + (wc + i * 16 + l15) * 64 + ch);
      }
#pragma unroll
    for (int kk = 0; kk < 2; ++kk)
#pragma unroll
      for (int mi = 0; mi < 4; ++mi)
#pragma unroll
        for (int ni = 0; ni < 4; ++ni)
          acc[mi][ni] = mfma16(af[kk][mi], bfr[kk][ni], acc[mi][ni]);
    __syncthreads();
  }

  const int crow = m0 + wr + lg * 4;
  const int ccol = n0 + wc + l15;
#pragma unroll
  for (int ni = 0; ni < 4; ++ni) {
    const int col = ccol + ni * 16;
    const float bv = bias[col];
#pragma unroll
    for (int mi = 0; mi < 4; ++mi)
#pragma unroll
      for (int r = 0; r < 4; ++r)
        Cout[(size_t)(crow + mi * 16 + r) * N + col] = acc[mi][ni][r] + bv;
  }
}

// ---------------- flash attention v11: R11 build + complement-chain perm -----
#define PACK_SUB(pp, dst)                                        \
  {                                                              \
    unsigned Aw = cvtpk(pp[0], pp[1]), Bw_ = cvtpk(pp[2], pp[3]);\
    unsigned Cw = cvtpk(pp[4], pp[5]), Dw = cvtpk(pp[6], pp[7]); \
    uint2v xc = __builtin_amdgcn_permlane32_swap(Aw, Cw, false, false); \
    uint2v yd = __builtin_amdgcn_permlane32_swap(Bw_, Dw, false, false);\
    dst[0] = xc[0]; dst[1] = yd[0]; dst[2] = xc[1]; dst[3] = yd[1];     \
    Aw = cvtpk(pp[8], pp[9]); Bw_ = cvtpk(pp[10], pp[11]);       \
    Cw = cvtpk(pp[12], pp[13]); Dw = cvtpk(pp[14], pp[15]);      \
    xc = __builtin_amdgcn_permlane32_swap(Aw, Cw, false, false); \
    yd = __builtin_amdgcn_permlane32_swap(Bw_, Dw, false, false);\
    dst[4] = xc[0]; dst[5] = yd[0]; dst[6] = xc[1]; dst[7] = yd[1];     \
  }

// One 32-s half-tile: QK^T, mask, exp2 (fixed max), l-sum, pack, PV.
#define HALF(ROFF, CB)                                                        \
  {                                                                           \
    f32x16 sa = {};                                                           \
    _Pragma("unroll")                                                         \
    for (int c = 0; c < 4; ++c) {                                             \
      bf16x8 ka = *(const bf16x8*)&Ks[kpar][(ROFF) + l31][c * 16 + hi * 8];   \
      sa = mfma32(ka, qf[c], sa);                                             \
    }                                                                         \
    if (s0 + (ROFF) + 31 > qw0) {                                             \
      _Pragma("unroll")                                                       \
      for (int r = 0; r < 16; ++r) {                                          \
        const int sl = s0 + (ROFF) + (r & 3) + 8 * (r >> 2) + 4 * hi;         \
        if (sl > q_abs) sa[r] = -1e30f;                                       \
      }                                                                       \
    }                                                                         \
    _Pragma("unroll")                                                         \
    for (int r = 0; r < 16; ++r) sa[r] = exp2f(sa[r]);                        \
    {                                                                         \
      float a0 = (sa[0] + sa[1]) + (sa[2] + sa[3]);                           \
      float a1 = (sa[4] + sa[5]) + (sa[6] + sa[7]);                           \
      float a2 = (sa[8] + sa[9]) + (sa[10] + sa[11]);                         \
      float a3 = (sa[12] + sa[13]) + (sa[14] + sa[15]);                       \
      l_s += (a0 + a1) + (a2 + a3);                                           \
    }                                                                         \
    unsigned pw[8];                                                           \
    PACK_SUB(sa, pw);                                                         \
    _Pragma("unroll")                                                         \
    for (int t4 = 0; t4 < 2; ++t4) {                                          \
      union { unsigned u[4]; bf16x8 v; } pb;                                  \
      pb.u[0] = pw[t4 * 4 + 0]; pb.u[1] = pw[t4 * 4 + 1];                     \
      pb.u[2] = pw[t4 * 4 + 2]; pb.u[3] = pw[t4 * 4 + 3];                     \
      bf16x8 va0 = *(const bf16x8*)&Vt[kpar][l31][((CB) + t4) * 16 + hi * 8]; \
      bf16x8 va1 = *(const bf16x8*)&Vt[kpar][32 + l31][((CB) + t4) * 16 + hi * 8];\
      ot0 = mfma32(va0, pb.v, ot0);                                           \
      ot1 = mfma32(va1, pb.v, ot1);                                           \
    }                                                                         \
  }

// block = 512 thr = 8 waves: qsub = w&3, kpar = w>>2 (tile t%2==kpar).
// Descending perm i128 = 15-j: with 2 resident blocks/CU, heavy residents
// retire ascending-np while backfill ids descend in np -> every CU chain
// sums ~17 tile-units (R4 perm gave chains 10..24 -> 35% occupancy decay).
__global__ __launch_bounds__(512, 4) void attn11(const short* __restrict__ qb,
                                                 const short* __restrict__ kb,
                                                 const short* __restrict__ vtg,
                                                 unsigned short* __restrict__ ob) {
  __shared__ __align__(16) union SmemU {
    struct { short Ks[2][64][72]; short Vt[2][64][72]; } s;   // 36864 B
    struct { float red[256 * 32]; float redl[256]; } r;       // 33792 B
  } sm;
  auto& Ks = sm.s.Ks;
  auto& Vt = sm.s.Vt;

  const int tid = threadIdx.x, w = tid >> 6, l = tid & 63;
  const int l31 = l & 31, hi = l >> 5;
  const int qsub = w & 3, kpar = w >> 2;
  const int id = blockIdx.x;
  const int bh = id & 63, j = id >> 6;
  const int i128 = 15 - j;               // descending: complement-chain balance
  const int b = bh >> 4, h = bh & 15, kv = h >> 2;
  const int q0 = i128 * 128;
  const int qw0 = q0 + qsub * 32;
  const int q_abs = qw0 + l31;

  const short* qp = qb + (size_t)(b * Tt + q_abs) * Cc + h * 64 + hi * 8;
  bf16x8 qf[4];
#pragma unroll
  for (int c = 0; c < 4; ++c) qf[c] = *(const bf16x8*)(qp + c * 16);

  f32x16 ot0 = {}, ot1 = {};
  float l_s = 0.f;

  // staging: tid 0..255 -> even tile of pair, 256..511 -> odd tile
  const int half512 = tid >> 8;           // 0 or 1
  const int srow = (tid & 255) >> 2, scol = (tid & 3) * 16;
  const short* kst = kb + (size_t)(b * Tt + srow) * KVdim + kv * 64 + scol;
  const short* vst = vtg + (size_t)((b * 4 + kv) * 64 + srow) * Tt + scol;

  const int ntiles = 2 * i128 + 2;

  // prologue: load pair 0 into regs (T14: reg-staged)
  bf16x8 rk0, rk1, rv0, rv1;
  {
    const short* ks = kst + (size_t)half512 * 64 * KVdim;
    const short* vs = vst + half512 * 64;
    rk0 = *(const bf16x8*)ks;  rk1 = *(const bf16x8*)(ks + 8);
    rv0 = *(const bf16x8*)vs;  rv1 = *(const bf16x8*)(vs + 8);
  }

  for (int tp = 0; tp < ntiles; tp += 2) {
    // write staged pair to LDS
    *(bf16x8*)&Ks[half512][srow][scol] = rk0;
    *(bf16x8*)&Ks[half512][srow][scol + 8] = rk1;
    *(bf16x8*)&Vt[half512][srow][scol] = rv0;
    *(bf16x8*)&Vt[half512][srow][scol + 8] = rv1;
    __syncthreads();
    // issue next pair's loads early (latency hides under compute)
    const int ts = tp + 2 + half512;
    if (ts < ntiles) {
      const short* ks = kst + (size_t)ts * 64 * KVdim;
      const short* vs = vst + ts * 64;
      rk0 = *(const bf16x8*)ks;  rk1 = *(const bf16x8*)(ks + 8);
      rv0 = *(const bf16x8*)vs;  rv1 = *(const bf16x8*)(vs + 8);
    }
    const int t = tp + kpar;
    if (t < ntiles) {
      const int s0 = t * 64;
      if (s0 <= qw0 + 31) {
        HALF(0, 0);
        if (s0 + 32 <= qw0 + 31) HALF(32, 2);
      }
    }
    __syncthreads();
  }

  // combine kpar partners via LDS (overlaid reduction space)
  // bank-conflict-free: per-lane chunk rotation cc=(c+l)&7 (same involution
  // on write and read)
  float* red = sm.r.red;
  float* redl = sm.r.redl;
  const int rot = l & 7;
  if (kpar == 1) {
    float* p = red + ((qsub * 64 + l) * 32);
#pragma unroll
    for (int c = 0; c < 8; ++c) {
      const int cc = ((c + rot) & 7) * 4;
      f32x4 v;
      if (c < 4) {
        v[0] = ot0[c * 4]; v[1] = ot0[c * 4 + 1];
        v[2] = ot0[c * 4 + 2]; v[3] = ot0[c * 4 + 3];
      } else {
        const int b0 = (c - 4) * 4;
        v[0] = ot1[b0]; v[1] = ot1[b0 + 1];
        v[2] = ot1[b0 + 2]; v[3] = ot1[b0 + 3];
      }
      *(f32x4*)(p + cc) = v;
    }
    redl[qsub * 64 + l] = l_s;
  }
  __syncthreads();
  if (kpar == 0) {
    const float* p = red + ((qsub * 64 + l) * 32);
#pragma unroll
    for (int c = 0; c < 8; ++c) {
      const int cc = ((c + rot) & 7) * 4;
      f32x4 v = *(const f32x4*)(p + cc);
      if (c < 4) {
        ot0[c * 4] += v[0]; ot0[c * 4 + 1] += v[1];
        ot0[c * 4 + 2] += v[2]; ot0[c * 4 + 3] += v[3];
      } else {
        const int b0 = (c - 4) * 4;
        ot1[b0] += v[0]; ot1[b0 + 1] += v[1];
        ot1[b0 + 2] += v[2]; ot1[b0 + 3] += v[3];
      }
    }
    l_s += redl[qsub * 64 + l];
    l_s += __shfl_xor(l_s, 32);
    const float inv = 1.f / l_s;
    unsigned short* op = ob + (size_t)(b * Tt + q_abs) * Cc + h * 64;
#pragma unroll
    for (int r = 0; r < 16; ++r) {
      const int d = (r & 3) + 8 * (r >> 2) + 4 * hi;
      op[d] = f2bf(ot0[r] * inv);
      op[32 + d] = f2bf(ot1[r] * inv);
    }
  }
}

extern "C" void kernel_launch(void* const* d_in, const int* in_sizes, int n_in,
                              void* d_out, int out_size, void* d_ws, size_t ws_size,
                              hipStream_t stream) {
  (void)in_sizes; (void)n_in; (void)out_size; (void)ws_size;
  const float* x  = (const float*)d_in[0];
  const float* Wq = (const float*)d_in[1];
  const float* bq = (const float*)d_in[2];
  const float* Wk = (const float*)d_in[3];
  const float* bk = (const float*)d_in[4];
  const float* Wv = (const float*)d_in[5];
  const float* bv = (const float*)d_in[6];
  const float* Wo = (const float*)d_in[7];
  const float* bo = (const float*)d_in[8];
  const float* gain = (const float*)d_in[9];
  float* out = (float*)d_out;

  char* ws = (char*)d_ws;
  short* xb  = (short*)ws;                    ws += (size_t)Mrows * Cc * 2;
  short* qbf = (short*)ws;                    ws += (size_t)Mrows * Cc * 2;
  short* kbf = (short*)ws;                    ws += (size_t)Mrows * KVdim * 2;
  short* vtg = (short*)ws;                    ws += (size_t)Mrows * KVdim * 2;
  short* atb = (short*)ws;                    ws += (size_t)Mrows * Cc * 2;
  short* wqb = (short*)ws;                    ws += (size_t)Cc * Cc * 2;
  short* wkb = (short*)ws;                    ws += (size_t)KVdim * Cc * 2;
  short* wvb = (short*)ws;                    ws += (size_t)KVdim * Cc * 2;
  short* wob = (short*)ws;                    ws += (size_t)Cc * Cc * 2;

  cvt_all<<<dim3(1024, 5), 256, 0, stream>>>(
      x, Wq, Wk, Wv, Wo,
      (unsigned short*)xb, (unsigned short*)wqb, (unsigned short*)wkb,
      (unsigned short*)wvb, (unsigned short*)wob,
      Mrows * Cc, Cc * Cc, KVdim * Cc, KVdim * Cc, Cc * Cc);

  qkv_gemm<<<dim3(Mrows / 128, 12), 256, 0, stream>>>(
      xb, wqb, wkb, wvb, bq, bk, bv, gain,
      (unsigned short*)qbf, (unsigned short*)kbf, (unsigned short*)vtg);

  attn11<<<1024, 512, 0, stream>>>(qbf, kbf, vtg, (unsigned short*)atb);

  gemm_o<<<dim3(Mrows / 128, Cc / 128), 256, 0, stream>>>(
      atb, wob, bo, out, Mrows, Cc, Cc);
}